// Round 4
// baseline (733.027 us; speedup 1.0000x reference)
//
#include <hip/hip_runtime.h>
#include <hip/hip_bf16.h>
#include <math.h>

typedef __hip_bfloat16 bf16;
typedef __hip_bfloat162 bf162;
typedef __attribute__((ext_vector_type(8))) short bf16x8;   // MFMA A/B frag (4 VGPRs)
typedef __attribute__((ext_vector_type(4))) short short4v;  // 8B store
typedef __attribute__((ext_vector_type(4))) float f32x4;    // MFMA C/D frag

__device__ __forceinline__ float b2f(bf16 x){ return __bfloat162float(x); }
__device__ __forceinline__ bf16  f2b(float x){ return __float2bfloat16(x); }
__device__ __forceinline__ short f2bs(float x){ bf16 h = __float2bfloat16(x); return *(short*)&h; }

constexpr int kH = 112, kW = 112, kC = 128, kHeads = 4, kWS = 7;
constexpr int kN = 49, kHD = 32, kL = kH * kW;      // L = 12544
constexpr int kWinElems = kN * kC;                  // 6272
constexpr int kMLP = 512;
constexpr float kEps = 1e-5f;
constexpr float kScale = 0.17677669529663687f;      // 1/sqrt(32)
constexpr int kAP = 136;      // LDS row stride (bf16) for k1: 272B = 17*16

// ---------------------------------------------------------------------------
// K0: convert all weight matrices fp32 -> bf16 into one ws arena.
__global__ __launch_bounds__(256) void k_cvt(
    const float* __restrict__ qw, const float* __restrict__ kvw,
    const float* __restrict__ pw, const float* __restrict__ w1,
    const float* __restrict__ w2, short* __restrict__ dst)
{
    const int i = blockIdx.x * 256 + threadIdx.x;   // 196608 total
    float val;
    if (i < 16384)       val = qw[i];
    else if (i < 49152)  val = kvw[i - 16384];
    else if (i < 65536)  val = pw[i - 49152];
    else if (i < 131072) val = w1[i - 65536];
    else                 val = w2[i - 131072];
    dst[i] = f2bs(val);
}

// ---------------------------------------------------------------------------
// K1 (MFMA): LN(x), LN(v) + Q/K/V projection + window-partition scatter.
__global__ __launch_bounds__(256) void k_ln_qkv_mfma(
    const float* __restrict__ x, const float* __restrict__ v,
    const float* __restrict__ n1g, const float* __restrict__ n1b,
    const float* __restrict__ nvg, const float* __restrict__ nvb,
    const short* __restrict__ qwb, const float* __restrict__ qb,
    const short* __restrict__ kvwb, const float* __restrict__ kvb,
    bf16* __restrict__ qo, bf16* __restrict__ ko, bf16* __restrict__ vo)
{
    __shared__ short Xs[32 * kAP], Vs[32 * kAP];
    const int tid = threadIdx.x, wave = tid >> 6, lane = tid & 63;
    const int quad = lane >> 4, l16 = lane & 15;
    const int row0 = blockIdx.x * 32;
    const int c0 = lane * 2;

    for (int n = wave; n < 32; n += 4) {
        const size_t r = (size_t)(row0 + n) * kC;
        const float2 xv = *(const float2*)(x + r + c0);
        const float2 vv = *(const float2*)(v + r + c0);
        float sx = xv.x + xv.y, qx = xv.x * xv.x + xv.y * xv.y;
        float sv = vv.x + vv.y, qv = vv.x * vv.x + vv.y * vv.y;
        #pragma unroll
        for (int off = 32; off > 0; off >>= 1) {
            sx += __shfl_xor(sx, off); qx += __shfl_xor(qx, off);
            sv += __shfl_xor(sv, off); qv += __shfl_xor(qv, off);
        }
        const float mux = sx * (1.f / kC);
        const float ivx = rsqrtf(qx * (1.f / kC) - mux * mux + kEps);
        const float muv = sv * (1.f / kC);
        const float ivv = rsqrtf(qv * (1.f / kC) - muv * muv + kEps);
        Xs[n * kAP + c0]     = f2bs((xv.x - mux) * ivx * n1g[c0] + n1b[c0]);
        Xs[n * kAP + c0 + 1] = f2bs((xv.y - mux) * ivx * n1g[c0 + 1] + n1b[c0 + 1]);
        Vs[n * kAP + c0]     = f2bs((vv.x - muv) * ivv * nvg[c0] + nvb[c0]);
        Vs[n * kAP + c0 + 1] = f2bs((vv.y - muv) * ivv * nvg[c0 + 1] + nvb[c0 + 1]);
    }
    __syncthreads();

    int woff[2];
    #pragma unroll
    for (int mt = 0; mt < 2; mt++) {
        const int gr = row0 + mt * 16 + l16;
        const int b = gr / kL, l = gr - b * kL;
        const int h = l / kW, w_ = l - h * kW;
        woff[mt] = ((b << 8) + (h / 7) * 16 + (w_ / 7)) * kWinElems
                 + ((h % 7) * 7 + (w_ % 7)) * kC;
    }

    bf16x8 xf[2][4], vf[2][4];
    #pragma unroll
    for (int mt = 0; mt < 2; mt++)
        #pragma unroll
        for (int ks = 0; ks < 4; ks++) {
            xf[mt][ks] = *(const bf16x8*)&Xs[(mt * 16 + l16) * kAP + ks * 32 + quad * 8];
            vf[mt][ks] = *(const bf16x8*)&Vs[(mt * 16 + l16) * kAP + ks * 32 + quad * 8];
        }

    #pragma unroll
    for (int j = 0; j < 6; j++) {
        const int nt = wave * 6 + j;
        const bool isq = (nt < 8);
        const short* wmat = isq ? qwb : kvwb;
        const int wr0 = (isq ? nt : nt - 8) * 16;
        const float* bias = isq ? qb : kvb;
        const int bidx = wr0 + quad * 4;
        f32x4 a0 = { bias[bidx], bias[bidx + 1], bias[bidx + 2], bias[bidx + 3] };
        f32x4 a1 = a0;
        if (isq) {
            #pragma unroll
            for (int ks = 0; ks < 4; ks++) {
                const bf16x8 af = *(const bf16x8*)(wmat + (size_t)(wr0 + l16) * kC + ks * 32 + quad * 8);
                a0 = __builtin_amdgcn_mfma_f32_16x16x32_bf16(af, xf[0][ks], a0, 0, 0, 0);
                a1 = __builtin_amdgcn_mfma_f32_16x16x32_bf16(af, xf[1][ks], a1, 0, 0, 0);
            }
        } else {
            #pragma unroll
            for (int ks = 0; ks < 4; ks++) {
                const bf16x8 af = *(const bf16x8*)(wmat + (size_t)(wr0 + l16) * kC + ks * 32 + quad * 8);
                a0 = __builtin_amdgcn_mfma_f32_16x16x32_bf16(af, vf[0][ks], a0, 0, 0, 0);
                a1 = __builtin_amdgcn_mfma_f32_16x16x32_bf16(af, vf[1][ks], a1, 0, 0, 0);
            }
        }
        bf16* dst = isq ? qo : (nt < 16 ? ko : vo);
        const int cb = (isq ? nt : (nt < 16 ? nt - 8 : nt - 16)) * 16 + quad * 4;
        short4v p0, p1;
        #pragma unroll
        for (int i = 0; i < 4; i++) { p0[i] = f2bs(a0[i]); p1[i] = f2bs(a1[i]); }
        *(short4v*)((short*)dst + (size_t)woff[0] + cb) = p0;
        *(short4v*)((short*)dst + (size_t)woff[1] + cb) = p1;
    }
}

// ---------------------------------------------------------------------------
// K2 (MFMA): attention per window; wave = head.
__global__ __launch_bounds__(256, 3) void k_attn_mfma(
    bf16* __restrict__ qbuf, const bf16* __restrict__ kbuf,
    const bf16* __restrict__ vbuf, const float* __restrict__ rpb)
{
    __shared__ short Pl[kHeads][64 * 64];   // P[n][m] bf16, swizzled (32 KB)
    __shared__ short Vt[kHeads][32 * 64];   // V^T[d][m] bf16, swizzled (16 KB)
    __shared__ float rpl[kHeads][169];      // rpb slice per head (2.7 KB)
    const int tid = threadIdx.x, wave = tid >> 6, lane = tid & 63;
    const int quad = lane >> 4, l16 = lane & 15;
    const int head = wave;
    const size_t wbase = (size_t)blockIdx.x * kWinElems;

    for (int i = lane; i < 169; i += 64) rpl[head][i] = rpb[i * kHeads + head];

    bf16x8 qf[4], kf[4];
    const bf16* qp = qbuf + wbase + head * kHD + quad * 8;
    const bf16* kp = kbuf + wbase + head * kHD + quad * 8;
    #pragma unroll
    for (int t = 0; t < 4; t++) {
        qf[t] = *(const bf16x8*)(qp + (size_t)(t * 16 + l16) * kC);
        kf[t] = *(const bf16x8*)(kp + (size_t)(t * 16 + l16) * kC);
    }

    #pragma unroll
    for (int h = 0; h < 4; h++) {
        for (int i = tid; i < 1024; i += 256) {       // 64 m-slots x 16 d-pairs
            const int m = i >> 4, d2 = (i & 15) << 1;
            int val = 0;
            if (m < 49) val = *(const int*)(vbuf + wbase + (size_t)m * kC + h * kHD + d2);
            Vt[h][d2 * 64 + (m ^ ((d2 & 7) << 3))]         = (short)(val & 0xffff);
            Vt[h][(d2 + 1) * 64 + (m ^ (((d2 + 1) & 7) << 3))] = (short)(val >> 16);
        }
    }

    f32x4 S[4][4];
    #pragma unroll
    for (int nt = 0; nt < 4; nt++)
        #pragma unroll
        for (int mt = 0; mt < 4; mt++)
            S[nt][mt] = __builtin_amdgcn_mfma_f32_16x16x32_bf16(
                qf[nt], kf[mt], (f32x4){0.f, 0.f, 0.f, 0.f}, 0, 0, 0);

    __syncthreads();   // Vt (cross-wave) ready

    int an[4][4];
    #pragma unroll
    for (int nt = 0; nt < 4; nt++)
        #pragma unroll
        for (int i = 0; i < 4; i++) {
            const int n = nt * 16 + quad * 4 + i;
            an[nt][i] = 13 * (n / 7) + (n % 7) + 84;
        }
    int bm[4]; bool mok[4];
    #pragma unroll
    for (int mt = 0; mt < 4; mt++) {
        const int m = mt * 16 + l16;
        bm[mt] = 13 * (m / 7) + (m % 7);
        mok[mt] = (m < 49);
    }

    const float* rp = rpl[head];
    #pragma unroll
    for (int nt = 0; nt < 4; nt++)
        #pragma unroll
        for (int i = 0; i < 4; i++) {
            float sv[4];
            #pragma unroll
            for (int mt = 0; mt < 4; mt++) {
                int idx = an[nt][i] - bm[mt];
                idx = ((unsigned)idx > 168u) ? 0 : idx;
                sv[mt] = mok[mt] ? (S[nt][mt][i] * kScale + rp[idx]) : -1e30f;
            }
            float mx = fmaxf(fmaxf(sv[0], sv[1]), fmaxf(sv[2], sv[3]));
            #pragma unroll
            for (int off = 1; off < 16; off <<= 1) mx = fmaxf(mx, __shfl_xor(mx, off));
            float e[4];
            float sum = 0.f;
            #pragma unroll
            for (int mt = 0; mt < 4; mt++) { e[mt] = __expf(sv[mt] - mx); sum += e[mt]; }
            #pragma unroll
            for (int off = 1; off < 16; off <<= 1) sum += __shfl_xor(sum, off);
            const float inv = 1.f / sum;
            const int prow = nt * 16 + quad * 4 + i;
            short* pr = &Pl[head][prow * 64];
            const int sw = (prow & 7) << 3;
            #pragma unroll
            for (int mt = 0; mt < 4; mt++)
                pr[(mt * 16 + l16) ^ sw] = f2bs(e[mt] * inv);
        }

    bf16x8 va[2][2], pb2[4][2];
    #pragma unroll
    for (int dt = 0; dt < 2; dt++)
        #pragma unroll
        for (int ks = 0; ks < 2; ks++) {
            const int r = dt * 16 + l16;
            va[dt][ks] = *(const bf16x8*)&Vt[head][r * 64 + ((ks * 32 + quad * 8) ^ ((r & 7) << 3))];
        }
    #pragma unroll
    for (int nt = 0; nt < 4; nt++)
        #pragma unroll
        for (int ks = 0; ks < 2; ks++) {
            const int r = nt * 16 + l16;
            pb2[nt][ks] = *(const bf16x8*)&Pl[head][r * 64 + ((ks * 32 + quad * 8) ^ ((r & 7) << 3))];
        }
    f32x4 o[2][4];
    #pragma unroll
    for (int dt = 0; dt < 2; dt++)
        #pragma unroll
        for (int nt = 0; nt < 4; nt++) {
            f32x4 a = __builtin_amdgcn_mfma_f32_16x16x32_bf16(
                va[dt][0], pb2[nt][0], (f32x4){0.f, 0.f, 0.f, 0.f}, 0, 0, 0);
            o[dt][nt] = __builtin_amdgcn_mfma_f32_16x16x32_bf16(
                va[dt][1], pb2[nt][1], a, 0, 0, 0);
        }

    #pragma unroll
    for (int nt = 0; nt < 4; nt++) {
        const int n = nt * 16 + l16;
        if (n < 49) {
            bf16* dst = qbuf + wbase + (size_t)n * kC + head * kHD + quad * 4;
            #pragma unroll
            for (int dt = 0; dt < 2; dt++) {
                short4v p;
                #pragma unroll
                for (int i = 0; i < 4; i++) p[i] = f2bs(o[dt][nt][i]);
                *(short4v*)(dst + dt * 16) = p;
            }
        }
    }
}

// ---------------------------------------------------------------------------
// K3+K4 fused v2: xo kept entirely in registers (proj D-layout == fc2 D-layout,
// channels (wave*2+j)*16+quad*4+i, rows mt*16+l16). LDS = A_s [32][128] +
// H_s [32][512], both XOR-swizzled (col ^ ((row&7)<<3)) = 40960 B -> 4 blk/CU.
// LN2 row-stats via quad-shuffle + 1KB cross-wave scratch (overlaid on H_s).
constexpr int kMT = 32;
constexpr int kAPs = 128;     // A_s row stride (shorts), swizzled
constexpr int kHPs = 512;     // H_s row stride (shorts), swizzled

__global__ __launch_bounds__(256, 4) void k_proj_mlp(
    const bf16* __restrict__ ao, const short* __restrict__ pwb,
    const float* __restrict__ pb, const float* __restrict__ x,
    float* __restrict__ out,
    const float* __restrict__ g2, const float* __restrict__ b2v,
    const short* __restrict__ w1b, const float* __restrict__ bb1,
    const short* __restrict__ w2b, const float* __restrict__ bb2)
{
    __shared__ short LDSu[kMT * kAPs + kMT * kHPs];   // 40960 B exactly
    short* const A_s = LDSu;                          // 8192 B
    short* const H_s = LDSu + kMT * kAPs;             // 32768 B
    float* const lnscr = (float*)H_s;                 // 1024 B, dead before H_s

    const int tid = threadIdx.x, wave = tid >> 6, lane = tid & 63;
    const int quad = lane >> 4, l16 = lane & 15;
    const size_t row0 = (size_t)blockIdx.x * kMT;
    const int xorm = (l16 & 7) << 3;                  // row-XOR in short units

    // ===== Phase A: direct windowed frag loads + proj + residual -> regs ====
    int woff[2];
    #pragma unroll
    for (int mt = 0; mt < 2; mt++) {
        const int gr = (int)row0 + mt * 16 + l16;
        const int b = gr / kL, l = gr - b * kL;
        const int h = l / kW, w_ = l - h * kW;
        woff[mt] = ((b << 8) + (h / 7) * 16 + (w_ / 7)) * kWinElems
                 + ((h % 7) * 7 + (w_ % 7)) * kC;
    }
    bf16x8 bfrag[2][4];
    #pragma unroll
    for (int mt = 0; mt < 2; mt++)
        #pragma unroll
        for (int ks = 0; ks < 4; ks++)
            bfrag[mt][ks] = *(const bf16x8*)((const short*)ao
                                + (size_t)woff[mt] + ks * 32 + quad * 8);

    float4 res[2][2];
    #pragma unroll
    for (int j = 0; j < 2; j++)
        #pragma unroll
        for (int mt = 0; mt < 2; mt++)
            res[j][mt] = *(const float4*)(x + (row0 + mt * 16 + l16) * kC
                                            + (wave * 2 + j) * 16 + quad * 4);
    float4 gv[2], bvv[2];
    #pragma unroll
    for (int j = 0; j < 2; j++) {
        const int cb = (wave * 2 + j) * 16 + quad * 4;
        gv[j]  = *(const float4*)(g2 + cb);
        bvv[j] = *(const float4*)(b2v + cb);
    }

    f32x4 xo[2][2];     // [j][mt]: rows mt*16+l16, chans (wave*2+j)*16+quad*4+i
    #pragma unroll
    for (int j = 0; j < 2; j++) {
        const int nt = wave * 2 + j;
        const int cb = nt * 16 + quad * 4;
        const float4 pbv = *(const float4*)(pb + cb);
        f32x4 a0 = { pbv.x, pbv.y, pbv.z, pbv.w };
        f32x4 a1 = a0;
        #pragma unroll
        for (int ks = 0; ks < 4; ks++) {
            const bf16x8 af = *(const bf16x8*)(pwb + (size_t)(nt * 16 + l16) * kC + ks * 32 + quad * 8);
            a0 = __builtin_amdgcn_mfma_f32_16x16x32_bf16(af, bfrag[0][ks], a0, 0, 0, 0);
            a1 = __builtin_amdgcn_mfma_f32_16x16x32_bf16(af, bfrag[1][ks], a1, 0, 0, 0);
        }
        #pragma unroll
        for (int i = 0; i < 4; i++) {
            xo[j][0][i] = a0[i] + ((const float*)&res[j][0])[i];
            xo[j][1][i] = a1[i] + ((const float*)&res[j][1])[i];
        }
    }

    // ===== Phase B: LN2 stats (quad shuffle + cross-wave scratch) ==========
    float sp[2], qp[2];
    #pragma unroll
    for (int mt = 0; mt < 2; mt++) {
        float s = 0.f, q = 0.f;
        #pragma unroll
        for (int j = 0; j < 2; j++)
            #pragma unroll
            for (int i = 0; i < 4; i++) {
                const float v = xo[j][mt][i];
                s += v; q += v * v;
            }
        s += __shfl_xor(s, 16); q += __shfl_xor(q, 16);
        s += __shfl_xor(s, 32); q += __shfl_xor(q, 32);
        sp[mt] = s; qp[mt] = q;
    }
    if (quad == 0) {
        #pragma unroll
        for (int mt = 0; mt < 2; mt++) {
            float2 pr; pr.x = sp[mt]; pr.y = qp[mt];
            *(float2*)&lnscr[(mt * 16 + l16) * 8 + wave * 2] = pr;
        }
    }
    __syncthreads();    // B1: scratch ready

    float mu[2], iv[2];
    #pragma unroll
    for (int mt = 0; mt < 2; mt++) {
        const int r = mt * 16 + l16;
        float s = 0.f, q = 0.f;
        #pragma unroll
        for (int w = 0; w < 4; w++) {
            const float2 pr = *(const float2*)&lnscr[r * 8 + w * 2];
            s += pr.x; q += pr.y;
        }
        mu[mt] = s * (1.f / kC);
        iv[mt] = rsqrtf(q * (1.f / kC) - mu[mt] * mu[mt] + kEps);
    }

    // normalized activations -> A_s (bf16, swizzled)
    #pragma unroll
    for (int j = 0; j < 2; j++) {
        const int cb = (wave * 2 + j) * 16 + quad * 4;
        #pragma unroll
        for (int mt = 0; mt < 2; mt++) {
            short4v p;
            #pragma unroll
            for (int i = 0; i < 4; i++)
                p[i] = f2bs((xo[j][mt][i] - mu[mt]) * iv[mt]
                            * ((const float*)&gv[j])[i] + ((const float*)&bvv[j])[i]);
            *(short4v*)&A_s[(mt * 16 + l16) * kAPs + (cb ^ xorm)] = p;
        }
    }
    __syncthreads();    // B2: A_s ready; lnscr reads done -> H_s region free

    bf16x8 bfrag2[2][4];
    #pragma unroll
    for (int mt = 0; mt < 2; mt++)
        #pragma unroll
        for (int ks = 0; ks < 4; ks++)
            bfrag2[mt][ks] = *(const bf16x8*)&A_s[(mt * 16 + l16) * kAPs
                                + ((ks * 32 + quad * 8) ^ xorm)];

    // ===== Phase C: fc1 + exact GELU -> H_s (swizzled) =====================
    const short* wbase = w1b + (size_t)(wave * 128 + l16) * kC + quad * 8;
    auto loadw1 = [&](bf16x8* dst, int t) {
        #pragma unroll
        for (int ks = 0; ks < 4; ks++)
            dst[ks] = *(const bf16x8*)(wbase + (size_t)t * (16 * kC) + ks * 32);
    };
    auto mfma8 = [&](f32x4* a, const bf16x8* w) {
        #pragma unroll
        for (int ks = 0; ks < 4; ks++) {
            a[0] = __builtin_amdgcn_mfma_f32_16x16x32_bf16(w[ks], bfrag2[0][ks], a[0], 0, 0, 0);
            a[1] = __builtin_amdgcn_mfma_f32_16x16x32_bf16(w[ks], bfrag2[1][ks], a[1], 0, 0, 0);
        }
    };
    #pragma unroll
    for (int g = 0; g < 2; g++) {
        f32x4 acc[4][2];
        #pragma unroll
        for (int t = 0; t < 4; t++) {
            const float4 bi = *(const float4*)(bb1 + (wave * 8 + g * 4 + t) * 16 + quad * 4);
            acc[t][0] = (f32x4){ bi.x, bi.y, bi.z, bi.w };
            acc[t][1] = acc[t][0];
        }
        bf16x8 wA[4], wB[4];
        loadw1(wA, g * 4 + 0);
        loadw1(wB, g * 4 + 1);
        mfma8(acc[0], wA);
        loadw1(wA, g * 4 + 2);
        mfma8(acc[1], wB);
        loadw1(wB, g * 4 + 3);
        mfma8(acc[2], wA);
        mfma8(acc[3], wB);
        #pragma unroll
        for (int t = 0; t < 4; t++) {
            const int nb = (wave * 8 + g * 4 + t) * 16 + quad * 4;
            #pragma unroll
            for (int mt = 0; mt < 2; mt++) {
                short4v p;
                #pragma unroll
                for (int i = 0; i < 4; i++) {
                    const float a = acc[t][mt][i];
                    p[i] = f2bs(0.5f * a * (1.f + erff(a * 0.70710678118f)));
                }
                *(short4v*)&H_s[(mt * 16 + l16) * kHPs + (nb ^ xorm)] = p;
            }
        }
    }
    __syncthreads();    // B3: H_s ready

    // ===== Phase D: fc2 + final write (xo regs + mlp) ======================
    const int ct0 = wave * 2;
    f32x4 acc2[2][2];
    #pragma unroll
    for (int t = 0; t < 2; t++) {
        const float4 bi = *(const float4*)(bb2 + (ct0 + t) * 16 + quad * 4);
        acc2[t][0] = (f32x4){ bi.x, bi.y, bi.z, bi.w };
        acc2[t][1] = acc2[t][0];
    }
    const short* w2base = w2b + (size_t)(ct0 * 16 + l16) * kMLP + quad * 8;
    const short* hb0 = &H_s[l16 * kHPs];
    const short* hb1 = &H_s[(16 + l16) * kHPs];
    auto loadh = [&](bf16x8* h, bf16x8* w, int kk) {
        const int col = (kk * 32 + quad * 8) ^ xorm;
        h[0] = *(const bf16x8*)(hb0 + col);
        h[1] = *(const bf16x8*)(hb1 + col);
        w[0] = *(const bf16x8*)(w2base + kk * 32);
        w[1] = *(const bf16x8*)(w2base + (size_t)16 * kMLP + kk * 32);
    };
    auto mfma4 = [&](const bf16x8* h, const bf16x8* w) {
        acc2[0][0] = __builtin_amdgcn_mfma_f32_16x16x32_bf16(w[0], h[0], acc2[0][0], 0, 0, 0);
        acc2[0][1] = __builtin_amdgcn_mfma_f32_16x16x32_bf16(w[0], h[1], acc2[0][1], 0, 0, 0);
        acc2[1][0] = __builtin_amdgcn_mfma_f32_16x16x32_bf16(w[1], h[0], acc2[1][0], 0, 0, 0);
        acc2[1][1] = __builtin_amdgcn_mfma_f32_16x16x32_bf16(w[1], h[1], acc2[1][1], 0, 0, 0);
    };
    bf16x8 hA[2], wwA[2], hB[2], wwB[2];
    loadh(hA, wwA, 0);
    #pragma unroll
    for (int kk = 0; kk < 16; kk += 2) {
        loadh(hB, wwB, kk + 1);
        mfma4(hA, wwA);
        if (kk + 2 < 16) loadh(hA, wwA, kk + 2);
        mfma4(hB, wwB);
    }

    #pragma unroll
    for (int t = 0; t < 2; t++) {
        const int cbv = (ct0 + t) * 16 + quad * 4;
        #pragma unroll
        for (int mt = 0; mt < 2; mt++) {
            const size_t m = row0 + mt * 16 + l16;
            float4 r;
            r.x = xo[t][mt][0] + acc2[t][mt][0];
            r.y = xo[t][mt][1] + acc2[t][mt][1];
            r.z = xo[t][mt][2] + acc2[t][mt][2];
            r.w = xo[t][mt][3] + acc2[t][mt][3];
            *(float4*)(out + m * kC + cbv) = r;
        }
    }
}

// ---------------------------------------------------------------------------
extern "C" void kernel_launch(void* const* d_in, const int* in_sizes, int n_in,
                              void* d_out, int out_size, void* d_ws, size_t ws_size,
                              hipStream_t stream) {
    (void)in_sizes; (void)n_in; (void)out_size; (void)ws_size;
    const float* x      = (const float*)d_in[0];
    const float* v      = (const float*)d_in[1];
    const float* n1g    = (const float*)d_in[2];
    const float* n1b    = (const float*)d_in[3];
    const float* nvg    = (const float*)d_in[4];
    const float* nvb    = (const float*)d_in[5];
    const float* q_w    = (const float*)d_in[6];
    const float* q_b    = (const float*)d_in[7];
    const float* kv_w   = (const float*)d_in[8];
    const float* kv_b   = (const float*)d_in[9];
    const float* rpb    = (const float*)d_in[10];
    const float* proj_w = (const float*)d_in[11];
    const float* proj_b = (const float*)d_in[12];
    const float* n2g    = (const float*)d_in[13];
    const float* n2b    = (const float*)d_in[14];
    const float* fc1_w  = (const float*)d_in[15];
    const float* fc1_b  = (const float*)d_in[16];
    const float* fc2_w  = (const float*)d_in[17];
    const float* fc2_b  = (const float*)d_in[18];

    const size_t winTot = (size_t)4096 * kWinElems;   // 25,690,112 elems
    bf16* qbuf = (bf16*)d_ws;
    bf16* kbuf = qbuf + winTot;
    bf16* vbuf = kbuf + winTot;                        // 154 MB
    short* wcvt = (short*)(vbuf + winTot);             // bf16 weight arena
    short* qwb  = wcvt;                                // 16384
    short* kvwb = qwb + 16384;                         // 32768
    short* pwb  = kvwb + 32768;                        // 16384
    short* w1b  = pwb + 16384;                         // 65536
    short* w2b  = w1b + 65536;                         // 65536
    float* outb = (float*)d_out;

    k_cvt<<<768, 256, 0, stream>>>(q_w, kv_w, proj_w, fc1_w, fc2_w, wcvt);
    k_ln_qkv_mfma<<<6272, 256, 0, stream>>>(x, v, n1g, n1b, nvg, nvb,
                                            qwb, q_b, kvwb, kv_b, qbuf, kbuf, vbuf);
    k_attn_mfma<<<4096, 256, 0, stream>>>(qbuf, kbuf, vbuf, rpb);
    k_proj_mlp<<<6272, 256, 0, stream>>>(qbuf, pwb, proj_b, x, outb,
                                         n2g, n2b, w1b, fc1_b, w2b, fc2_b);
}

// Round 6
// 705.103 us; speedup vs baseline: 1.0396x; 1.0396x over previous
//
#include <hip/hip_runtime.h>
#include <hip/hip_bf16.h>
#include <math.h>

typedef __hip_bfloat16 bf16;
typedef __hip_bfloat162 bf162;
typedef __attribute__((ext_vector_type(8))) short bf16x8;   // MFMA A/B frag (4 VGPRs)
typedef __attribute__((ext_vector_type(4))) short short4v;  // 8B store
typedef __attribute__((ext_vector_type(4))) float f32x4;    // MFMA C/D frag

__device__ __forceinline__ float b2f(bf16 x){ return __bfloat162float(x); }
__device__ __forceinline__ bf16  f2b(float x){ return __float2bfloat16(x); }
__device__ __forceinline__ short f2bs(float x){ bf16 h = __float2bfloat16(x); return *(short*)&h; }
__device__ __forceinline__ int pack2(float a, float b){
    return ((int)(unsigned short)f2bs(b) << 16) | (int)(unsigned short)f2bs(a);
}

constexpr int kH = 112, kW = 112, kC = 128, kHeads = 4, kWS = 7;
constexpr int kN = 49, kHD = 32, kL = kH * kW;      // L = 12544
constexpr int kWinElems = kN * kC;                  // 6272
constexpr int kMLP = 512;
constexpr float kEps = 1e-5f;
constexpr float kScale = 0.17677669529663687f;      // 1/sqrt(32)
constexpr int kAP = 136;      // LDS row stride (bf16) for k1: 272B = 17*16

// ---------------------------------------------------------------------------
// K0: convert all weight matrices fp32 -> bf16 into one ws arena.
__global__ __launch_bounds__(256) void k_cvt(
    const float* __restrict__ qw, const float* __restrict__ kvw,
    const float* __restrict__ pw, const float* __restrict__ w1,
    const float* __restrict__ w2, short* __restrict__ dst)
{
    const int i = blockIdx.x * 256 + threadIdx.x;   // 196608 total
    float val;
    if (i < 16384)       val = qw[i];
    else if (i < 49152)  val = kvw[i - 16384];
    else if (i < 65536)  val = pw[i - 49152];
    else if (i < 131072) val = w1[i - 65536];
    else                 val = w2[i - 131072];
    dst[i] = f2bs(val);
}

// ---------------------------------------------------------------------------
// K1 (MFMA): LN(x), LN(v) + Q/K/V projection + window-partition scatter.
// v2: batched LN loads + interleaved shuffle chains, hoisted gamma/beta,
// depth-1 weight double-buffer, float4 bias loads.
__global__ __launch_bounds__(256) void k_ln_qkv_mfma(
    const float* __restrict__ x, const float* __restrict__ v,
    const float* __restrict__ n1g, const float* __restrict__ n1b,
    const float* __restrict__ nvg, const float* __restrict__ nvb,
    const short* __restrict__ qwb, const float* __restrict__ qb,
    const short* __restrict__ kvwb, const float* __restrict__ kvb,
    bf16* __restrict__ qo, bf16* __restrict__ ko, bf16* __restrict__ vo)
{
    __shared__ short Xs[32 * kAP], Vs[32 * kAP];
    const int tid = threadIdx.x, wave = tid >> 6, lane = tid & 63;
    const int quad = lane >> 4, l16 = lane & 15;
    const int row0 = blockIdx.x * 32;
    const int c0 = lane * 2;

    // ---- LN: batch all loads, run 32 reduction chains interleaved ----
    const float g1a = n1g[c0], g1b = n1g[c0 + 1];
    const float b1a = n1b[c0], b1b = n1b[c0 + 1];
    const float gva = nvg[c0], gvb = nvg[c0 + 1];
    const float bva = nvb[c0], bvb = nvb[c0 + 1];
    float2 xv[8], vv[8];
    #pragma unroll
    for (int it = 0; it < 8; it++) {
        const size_t r = (size_t)(row0 + wave + it * 4) * kC;
        xv[it] = *(const float2*)(x + r + c0);
        vv[it] = *(const float2*)(v + r + c0);
    }
    float sx[8], qx[8], sv[8], qv[8];
    #pragma unroll
    for (int it = 0; it < 8; it++) {
        sx[it] = xv[it].x + xv[it].y; qx[it] = xv[it].x * xv[it].x + xv[it].y * xv[it].y;
        sv[it] = vv[it].x + vv[it].y; qv[it] = vv[it].x * vv[it].x + vv[it].y * vv[it].y;
    }
    #pragma unroll
    for (int off = 32; off > 0; off >>= 1) {
        #pragma unroll
        for (int it = 0; it < 8; it++) {
            sx[it] += __shfl_xor(sx[it], off); qx[it] += __shfl_xor(qx[it], off);
            sv[it] += __shfl_xor(sv[it], off); qv[it] += __shfl_xor(qv[it], off);
        }
    }
    #pragma unroll
    for (int it = 0; it < 8; it++) {
        const int n = wave + it * 4;
        const float mux = sx[it] * (1.f / kC);
        const float ivx = rsqrtf(qx[it] * (1.f / kC) - mux * mux + kEps);
        const float muv = sv[it] * (1.f / kC);
        const float ivv = rsqrtf(qv[it] * (1.f / kC) - muv * muv + kEps);
        *(int*)&Xs[n * kAP + c0] = pack2((xv[it].x - mux) * ivx * g1a + b1a,
                                         (xv[it].y - mux) * ivx * g1b + b1b);
        *(int*)&Vs[n * kAP + c0] = pack2((vv[it].x - muv) * ivv * gva + bva,
                                         (vv[it].y - muv) * ivv * gvb + bvb);
    }
    __syncthreads();

    // ---- windowed scatter offsets ----
    int woff[2];
    #pragma unroll
    for (int mt = 0; mt < 2; mt++) {
        const int gr = row0 + mt * 16 + l16;
        const int b = gr / kL, l = gr - b * kL;
        const int h = l / kW, w_ = l - h * kW;
        woff[mt] = ((b << 8) + (h / 7) * 16 + (w_ / 7)) * kWinElems
                 + ((h % 7) * 7 + (w_ % 7)) * kC;
    }

    // ---- preload activation B-fragments ----
    bf16x8 xf[2][4], vf[2][4];
    #pragma unroll
    for (int mt = 0; mt < 2; mt++)
        #pragma unroll
        for (int ks = 0; ks < 4; ks++) {
            xf[mt][ks] = *(const bf16x8*)&Xs[(mt * 16 + l16) * kAP + ks * 32 + quad * 8];
            vf[mt][ks] = *(const bf16x8*)&Vs[(mt * 16 + l16) * kAP + ks * 32 + quad * 8];
        }

    // ---- 24 out-channel tiles (q:0-7, k:8-15, v:16-23), 6/wave, dbuf ----
    auto loadw = [&](bf16x8* dst, int j) {
        const int nt = wave * 6 + j;
        const bool isq = (nt < 8);
        const short* wmat = isq ? qwb : kvwb;
        const int wr0 = (isq ? nt : nt - 8) * 16;
        #pragma unroll
        for (int ks = 0; ks < 4; ks++)
            dst[ks] = *(const bf16x8*)(wmat + (size_t)(wr0 + l16) * kC + ks * 32 + quad * 8);
    };
    bf16x8 wA[4], wB[4];
    loadw(wA, 0);
    #pragma unroll
    for (int j = 0; j < 6; j++) {
        if (j < 5) loadw((j & 1) ? wA : wB, j + 1);      // depth-1 prefetch
        const bf16x8* wc = (j & 1) ? wB : wA;
        const int nt = wave * 6 + j;
        const bool isq = (nt < 8);
        const float* bias = isq ? qb : kvb;
        const int wr0 = (isq ? nt : nt - 8) * 16;
        const float4 bv4 = *(const float4*)(bias + wr0 + quad * 4);
        f32x4 a0 = { bv4.x, bv4.y, bv4.z, bv4.w };
        f32x4 a1 = a0;
        if (isq) {
            #pragma unroll
            for (int ks = 0; ks < 4; ks++) {
                a0 = __builtin_amdgcn_mfma_f32_16x16x32_bf16(wc[ks], xf[0][ks], a0, 0, 0, 0);
                a1 = __builtin_amdgcn_mfma_f32_16x16x32_bf16(wc[ks], xf[1][ks], a1, 0, 0, 0);
            }
        } else {
            #pragma unroll
            for (int ks = 0; ks < 4; ks++) {
                a0 = __builtin_amdgcn_mfma_f32_16x16x32_bf16(wc[ks], vf[0][ks], a0, 0, 0, 0);
                a1 = __builtin_amdgcn_mfma_f32_16x16x32_bf16(wc[ks], vf[1][ks], a1, 0, 0, 0);
            }
        }
        bf16* dst = isq ? qo : (nt < 16 ? ko : vo);
        const int cb = (isq ? nt : (nt < 16 ? nt - 8 : nt - 16)) * 16 + quad * 4;
        short4v p0, p1;
        #pragma unroll
        for (int i = 0; i < 4; i++) { p0[i] = f2bs(a0[i]); p1[i] = f2bs(a1[i]); }
        *(short4v*)((short*)dst + (size_t)woff[0] + cb) = p0;
        *(short4v*)((short*)dst + (size_t)woff[1] + cb) = p1;
    }
}

// ---------------------------------------------------------------------------
// K2 (MFMA): attention per window; wave = head.
__global__ __launch_bounds__(256, 3) void k_attn_mfma(
    bf16* __restrict__ qbuf, const bf16* __restrict__ kbuf,
    const bf16* __restrict__ vbuf, const float* __restrict__ rpb)
{
    __shared__ short Pl[kHeads][64 * 64];   // P[n][m] bf16, swizzled (32 KB)
    __shared__ short Vt[kHeads][32 * 64];   // V^T[d][m] bf16, swizzled (16 KB)
    __shared__ float rpl[kHeads][169];      // rpb slice per head (2.7 KB)
    const int tid = threadIdx.x, wave = tid >> 6, lane = tid & 63;
    const int quad = lane >> 4, l16 = lane & 15;
    const int head = wave;
    const size_t wbase = (size_t)blockIdx.x * kWinElems;

    for (int i = lane; i < 169; i += 64) rpl[head][i] = rpb[i * kHeads + head];

    bf16x8 qf[4], kf[4];
    const bf16* qp = qbuf + wbase + head * kHD + quad * 8;
    const bf16* kp = kbuf + wbase + head * kHD + quad * 8;
    #pragma unroll
    for (int t = 0; t < 4; t++) {
        qf[t] = *(const bf16x8*)(qp + (size_t)(t * 16 + l16) * kC);
        kf[t] = *(const bf16x8*)(kp + (size_t)(t * 16 + l16) * kC);
    }

    #pragma unroll
    for (int h = 0; h < 4; h++) {
        for (int i = tid; i < 1024; i += 256) {       // 64 m-slots x 16 d-pairs
            const int m = i >> 4, d2 = (i & 15) << 1;
            int val = 0;
            if (m < 49) val = *(const int*)(vbuf + wbase + (size_t)m * kC + h * kHD + d2);
            Vt[h][d2 * 64 + (m ^ ((d2 & 7) << 3))]         = (short)(val & 0xffff);
            Vt[h][(d2 + 1) * 64 + (m ^ (((d2 + 1) & 7) << 3))] = (short)(val >> 16);
        }
    }

    f32x4 S[4][4];
    #pragma unroll
    for (int nt = 0; nt < 4; nt++)
        #pragma unroll
        for (int mt = 0; mt < 4; mt++)
            S[nt][mt] = __builtin_amdgcn_mfma_f32_16x16x32_bf16(
                qf[nt], kf[mt], (f32x4){0.f, 0.f, 0.f, 0.f}, 0, 0, 0);

    __syncthreads();   // Vt (cross-wave) ready

    int an[4][4];
    #pragma unroll
    for (int nt = 0; nt < 4; nt++)
        #pragma unroll
        for (int i = 0; i < 4; i++) {
            const int n = nt * 16 + quad * 4 + i;
            an[nt][i] = 13 * (n / 7) + (n % 7) + 84;
        }
    int bm[4]; bool mok[4];
    #pragma unroll
    for (int mt = 0; mt < 4; mt++) {
        const int m = mt * 16 + l16;
        bm[mt] = 13 * (m / 7) + (m % 7);
        mok[mt] = (m < 49);
    }

    const float* rp = rpl[head];
    #pragma unroll
    for (int nt = 0; nt < 4; nt++)
        #pragma unroll
        for (int i = 0; i < 4; i++) {
            float sv[4];
            #pragma unroll
            for (int mt = 0; mt < 4; mt++) {
                int idx = an[nt][i] - bm[mt];
                idx = ((unsigned)idx > 168u) ? 0 : idx;
                sv[mt] = mok[mt] ? (S[nt][mt][i] * kScale + rp[idx]) : -1e30f;
            }
            float mx = fmaxf(fmaxf(sv[0], sv[1]), fmaxf(sv[2], sv[3]));
            #pragma unroll
            for (int off = 1; off < 16; off <<= 1) mx = fmaxf(mx, __shfl_xor(mx, off));
            float e[4];
            float sum = 0.f;
            #pragma unroll
            for (int mt = 0; mt < 4; mt++) { e[mt] = __expf(sv[mt] - mx); sum += e[mt]; }
            #pragma unroll
            for (int off = 1; off < 16; off <<= 1) sum += __shfl_xor(sum, off);
            const float inv = 1.f / sum;
            const int prow = nt * 16 + quad * 4 + i;
            short* pr = &Pl[head][prow * 64];
            const int sw = (prow & 7) << 3;
            #pragma unroll
            for (int mt = 0; mt < 4; mt++)
                pr[(mt * 16 + l16) ^ sw] = f2bs(e[mt] * inv);
        }

    bf16x8 va[2][2], pb2[4][2];
    #pragma unroll
    for (int dt = 0; dt < 2; dt++)
        #pragma unroll
        for (int ks = 0; ks < 2; ks++) {
            const int r = dt * 16 + l16;
            va[dt][ks] = *(const bf16x8*)&Vt[head][r * 64 + ((ks * 32 + quad * 8) ^ ((r & 7) << 3))];
        }
    #pragma unroll
    for (int nt = 0; nt < 4; nt++)
        #pragma unroll
        for (int ks = 0; ks < 2; ks++) {
            const int r = nt * 16 + l16;
            pb2[nt][ks] = *(const bf16x8*)&Pl[head][r * 64 + ((ks * 32 + quad * 8) ^ ((r & 7) << 3))];
        }
    f32x4 o[2][4];
    #pragma unroll
    for (int dt = 0; dt < 2; dt++)
        #pragma unroll
        for (int nt = 0; nt < 4; nt++) {
            f32x4 a = __builtin_amdgcn_mfma_f32_16x16x32_bf16(
                va[dt][0], pb2[nt][0], (f32x4){0.f, 0.f, 0.f, 0.f}, 0, 0, 0);
            o[dt][nt] = __builtin_amdgcn_mfma_f32_16x16x32_bf16(
                va[dt][1], pb2[nt][1], a, 0, 0, 0);
        }

    #pragma unroll
    for (int nt = 0; nt < 4; nt++) {
        const int n = nt * 16 + l16;
        if (n < 49) {
            bf16* dst = qbuf + wbase + (size_t)n * kC + head * kHD + quad * 4;
            #pragma unroll
            for (int dt = 0; dt < 2; dt++) {
                short4v p;
                #pragma unroll
                for (int i = 0; i < 4; i++) p[i] = f2bs(o[dt][nt][i]);
                *(short4v*)(dst + dt * 16) = p;
            }
        }
    }
}

// ---------------------------------------------------------------------------
// K3+K4 fused v3: xo in registers; fc1 t-granular (8 VGPR acc live) to stay
// under the 128-VGPR cap of launch_bounds(256,4) -- R3's 4-tile acc spilled
// 16 B/thread to scratch (WRITE_SIZE +25 MB). LDS 40960 B -> 4 blk/CU.
constexpr int kMT = 32;
constexpr int kAPs = 128;     // A_s row stride (shorts), swizzled
constexpr int kHPs = 512;     // H_s row stride (shorts), swizzled

__global__ __launch_bounds__(256, 4) void k_proj_mlp(
    const bf16* __restrict__ ao, const short* __restrict__ pwb,
    const float* __restrict__ pb, const float* __restrict__ x,
    float* __restrict__ out,
    const float* __restrict__ g2, const float* __restrict__ b2v,
    const short* __restrict__ w1b, const float* __restrict__ bb1,
    const short* __restrict__ w2b, const float* __restrict__ bb2)
{
    __shared__ short LDSu[kMT * kAPs + kMT * kHPs];   // 40960 B exactly
    short* const A_s = LDSu;                          // 8192 B
    short* const H_s = LDSu + kMT * kAPs;             // 32768 B
    float* const lnscr = (float*)H_s;                 // 1024 B, dead before H_s

    const int tid = threadIdx.x, wave = tid >> 6, lane = tid & 63;
    const int quad = lane >> 4, l16 = lane & 15;
    const size_t row0 = (size_t)blockIdx.x * kMT;
    const int xorm = (l16 & 7) << 3;                  // row-XOR in short units

    // ===== Phase A: direct windowed frag loads + proj + residual -> regs ====
    int woff[2];
    #pragma unroll
    for (int mt = 0; mt < 2; mt++) {
        const int gr = (int)row0 + mt * 16 + l16;
        const int b = gr / kL, l = gr - b * kL;
        const int h = l / kW, w_ = l - h * kW;
        woff[mt] = ((b << 8) + (h / 7) * 16 + (w_ / 7)) * kWinElems
                 + ((h % 7) * 7 + (w_ % 7)) * kC;
    }
    bf16x8 bfrag[2][4];
    #pragma unroll
    for (int mt = 0; mt < 2; mt++)
        #pragma unroll
        for (int ks = 0; ks < 4; ks++)
            bfrag[mt][ks] = *(const bf16x8*)((const short*)ao
                                + (size_t)woff[mt] + ks * 32 + quad * 8);

    float4 res[2][2];
    #pragma unroll
    for (int j = 0; j < 2; j++)
        #pragma unroll
        for (int mt = 0; mt < 2; mt++)
            res[j][mt] = *(const float4*)(x + (row0 + mt * 16 + l16) * kC
                                            + (wave * 2 + j) * 16 + quad * 4);
    float4 gv[2], bvv[2];
    #pragma unroll
    for (int j = 0; j < 2; j++) {
        const int cb = (wave * 2 + j) * 16 + quad * 4;
        gv[j]  = *(const float4*)(g2 + cb);
        bvv[j] = *(const float4*)(b2v + cb);
    }

    f32x4 xo[2][2];     // [j][mt]: rows mt*16+l16, chans (wave*2+j)*16+quad*4+i
    #pragma unroll
    for (int j = 0; j < 2; j++) {
        const int nt = wave * 2 + j;
        const int cb = nt * 16 + quad * 4;
        const float4 pbv = *(const float4*)(pb + cb);
        f32x4 a0 = { pbv.x, pbv.y, pbv.z, pbv.w };
        f32x4 a1 = a0;
        #pragma unroll
        for (int ks = 0; ks < 4; ks++) {
            const bf16x8 af = *(const bf16x8*)(pwb + (size_t)(nt * 16 + l16) * kC + ks * 32 + quad * 8);
            a0 = __builtin_amdgcn_mfma_f32_16x16x32_bf16(af, bfrag[0][ks], a0, 0, 0, 0);
            a1 = __builtin_amdgcn_mfma_f32_16x16x32_bf16(af, bfrag[1][ks], a1, 0, 0, 0);
        }
        #pragma unroll
        for (int i = 0; i < 4; i++) {
            xo[j][0][i] = a0[i] + ((const float*)&res[j][0])[i];
            xo[j][1][i] = a1[i] + ((const float*)&res[j][1])[i];
        }
    }

    // ===== Phase B: LN2 stats (quad shuffle + cross-wave scratch) ==========
    float sp[2], qp[2];
    #pragma unroll
    for (int mt = 0; mt < 2; mt++) {
        float s = 0.f, q = 0.f;
        #pragma unroll
        for (int j = 0; j < 2; j++)
            #pragma unroll
            for (int i = 0; i < 4; i++) {
                const float v = xo[j][mt][i];
                s += v; q += v * v;
            }
        s += __shfl_xor(s, 16); q += __shfl_xor(q, 16);
        s += __shfl_xor(s, 32); q += __shfl_xor(q, 32);
        sp[mt] = s; qp[mt] = q;
    }
    if (quad == 0) {
        #pragma unroll
        for (int mt = 0; mt < 2; mt++) {
            float2 pr; pr.x = sp[mt]; pr.y = qp[mt];
            *(float2*)&lnscr[(mt * 16 + l16) * 8 + wave * 2] = pr;
        }
    }
    __syncthreads();    // B1: scratch ready

    float mu[2], iv[2];
    #pragma unroll
    for (int mt = 0; mt < 2; mt++) {
        const int r = mt * 16 + l16;
        float s = 0.f, q = 0.f;
        #pragma unroll
        for (int w = 0; w < 4; w++) {
            const float2 pr = *(const float2*)&lnscr[r * 8 + w * 2];
            s += pr.x; q += pr.y;
        }
        mu[mt] = s * (1.f / kC);
        iv[mt] = rsqrtf(q * (1.f / kC) - mu[mt] * mu[mt] + kEps);
    }

    // normalized activations -> A_s (bf16, swizzled)
    #pragma unroll
    for (int j = 0; j < 2; j++) {
        const int cb = (wave * 2 + j) * 16 + quad * 4;
        #pragma unroll
        for (int mt = 0; mt < 2; mt++) {
            short4v p;
            #pragma unroll
            for (int i = 0; i < 4; i++)
                p[i] = f2bs((xo[j][mt][i] - mu[mt]) * iv[mt]
                            * ((const float*)&gv[j])[i] + ((const float*)&bvv[j])[i]);
            *(short4v*)&A_s[(mt * 16 + l16) * kAPs + (cb ^ xorm)] = p;
        }
    }
    __syncthreads();    // B2: A_s ready; lnscr reads done -> H_s region free

    bf16x8 bfrag2[2][4];
    #pragma unroll
    for (int mt = 0; mt < 2; mt++)
        #pragma unroll
        for (int ks = 0; ks < 4; ks++)
            bfrag2[mt][ks] = *(const bf16x8*)&A_s[(mt * 16 + l16) * kAPs
                                + ((ks * 32 + quad * 8) ^ xorm)];

    // ===== Phase C: fc1 + exact GELU -> H_s, t-granular, dbuf prefetch =====
    const short* wbase = w1b + (size_t)(wave * 128 + l16) * kC + quad * 8;
    auto loadw1 = [&](bf16x8* dst, int t) {
        #pragma unroll
        for (int ks = 0; ks < 4; ks++)
            dst[ks] = *(const bf16x8*)(wbase + (size_t)t * (16 * kC) + ks * 32);
    };
    bf16x8 wA[4], wB[4];
    loadw1(wA, 0);
    #pragma unroll
    for (int t = 0; t < 8; t++) {
        if (t < 7) loadw1((t & 1) ? wA : wB, t + 1);   // depth-1 prefetch
        const bf16x8* wc = (t & 1) ? wB : wA;
        const float4 bi = *(const float4*)(bb1 + (wave * 8 + t) * 16 + quad * 4);
        f32x4 a0 = { bi.x, bi.y, bi.z, bi.w };
        f32x4 a1 = a0;
        #pragma unroll
        for (int ks = 0; ks < 4; ks++) {
            a0 = __builtin_amdgcn_mfma_f32_16x16x32_bf16(wc[ks], bfrag2[0][ks], a0, 0, 0, 0);
            a1 = __builtin_amdgcn_mfma_f32_16x16x32_bf16(wc[ks], bfrag2[1][ks], a1, 0, 0, 0);
        }
        const int nb = (wave * 8 + t) * 16 + quad * 4;
        short4v p0, p1;
        #pragma unroll
        for (int i = 0; i < 4; i++) {
            const float v0 = a0[i], v1 = a1[i];
            p0[i] = f2bs(0.5f * v0 * (1.f + erff(v0 * 0.70710678118f)));
            p1[i] = f2bs(0.5f * v1 * (1.f + erff(v1 * 0.70710678118f)));
        }
        *(short4v*)&H_s[l16 * kHPs + (nb ^ xorm)] = p0;
        *(short4v*)&H_s[(16 + l16) * kHPs + (nb ^ xorm)] = p1;
    }
    __syncthreads();    // B3: H_s ready

    // ===== Phase D: fc2 + final write (xo regs + mlp) ======================
    const int ct0 = wave * 2;
    f32x4 acc2[2][2];
    #pragma unroll
    for (int t = 0; t < 2; t++) {
        const float4 bi = *(const float4*)(bb2 + (ct0 + t) * 16 + quad * 4);
        acc2[t][0] = (f32x4){ bi.x, bi.y, bi.z, bi.w };
        acc2[t][1] = acc2[t][0];
    }
    const short* w2base = w2b + (size_t)(ct0 * 16 + l16) * kMLP + quad * 8;
    const short* hb0 = &H_s[l16 * kHPs];
    const short* hb1 = &H_s[(16 + l16) * kHPs];
    auto loadh = [&](bf16x8* h, bf16x8* w, int kk) {
        const int col = (kk * 32 + quad * 8) ^ xorm;
        h[0] = *(const bf16x8*)(hb0 + col);
        h[1] = *(const bf16x8*)(hb1 + col);
        w[0] = *(const bf16x8*)(w2base + kk * 32);
        w[1] = *(const bf16x8*)(w2base + (size_t)16 * kMLP + kk * 32);
    };
    auto mfma4 = [&](const bf16x8* h, const bf16x8* w) {
        acc2[0][0] = __builtin_amdgcn_mfma_f32_16x16x32_bf16(w[0], h[0], acc2[0][0], 0, 0, 0);
        acc2[0][1] = __builtin_amdgcn_mfma_f32_16x16x32_bf16(w[0], h[1], acc2[0][1], 0, 0, 0);
        acc2[1][0] = __builtin_amdgcn_mfma_f32_16x16x32_bf16(w[1], h[0], acc2[1][0], 0, 0, 0);
        acc2[1][1] = __builtin_amdgcn_mfma_f32_16x16x32_bf16(w[1], h[1], acc2[1][1], 0, 0, 0);
    };
    bf16x8 hA[2], wwA[2], hB[2], wwB[2];
    loadh(hA, wwA, 0);
    #pragma unroll
    for (int kk = 0; kk < 16; kk += 2) {
        loadh(hB, wwB, kk + 1);
        mfma4(hA, wwA);
        if (kk + 2 < 16) loadh(hA, wwA, kk + 2);
        mfma4(hB, wwB);
    }

    #pragma unroll
    for (int t = 0; t < 2; t++) {
        const int cbv = (ct0 + t) * 16 + quad * 4;
        #pragma unroll
        for (int mt = 0; mt < 2; mt++) {
            const size_t m = row0 + mt * 16 + l16;
            float4 r;
            r.x = xo[t][mt][0] + acc2[t][mt][0];
            r.y = xo[t][mt][1] + acc2[t][mt][1];
            r.z = xo[t][mt][2] + acc2[t][mt][2];
            r.w = xo[t][mt][3] + acc2[t][mt][3];
            *(float4*)(out + m * kC + cbv) = r;
        }
    }
}

// ---------------------------------------------------------------------------
extern "C" void kernel_launch(void* const* d_in, const int* in_sizes, int n_in,
                              void* d_out, int out_size, void* d_ws, size_t ws_size,
                              hipStream_t stream) {
    (void)in_sizes; (void)n_in; (void)out_size; (void)ws_size;
    const float* x      = (const float*)d_in[0];
    const float* v      = (const float*)d_in[1];
    const float* n1g    = (const float*)d_in[2];
    const float* n1b    = (const float*)d_in[3];
    const float* nvg    = (const float*)d_in[4];
    const float* nvb    = (const float*)d_in[5];
    const float* q_w    = (const float*)d_in[6];
    const float* q_b    = (const float*)d_in[7];
    const float* kv_w   = (const float*)d_in[8];
    const float* kv_b   = (const float*)d_in[9];
    const float* rpb    = (const float*)d_in[10];
    const float* proj_w = (const float*)d_in[11];
    const float* proj_b = (const float*)d_in[12];
    const float* n2g    = (const float*)d_in[13];
    const float* n2b    = (const float*)d_in[14];
    const float* fc1_w  = (const float*)d_in[15];
    const float* fc1_b  = (const float*)d_in[16];
    const float* fc2_w  = (const float*)d_in[17];
    const float* fc2_b  = (const float*)d_in[18];

    const size_t winTot = (size_t)4096 * kWinElems;   // 25,690,112 elems
    bf16* qbuf = (bf16*)d_ws;
    bf16* kbuf = qbuf + winTot;
    bf16* vbuf = kbuf + winTot;                        // 154 MB
    short* wcvt = (short*)(vbuf + winTot);             // bf16 weight arena
    short* qwb  = wcvt;                                // 16384
    short* kvwb = qwb + 16384;                         // 32768
    short* pwb  = kvwb + 32768;                        // 16384
    short* w1b  = pwb + 16384;                         // 65536
    short* w2b  = w1b + 65536;                         // 65536
    float* outb = (float*)d_out;

    k_cvt<<<768, 256, 0, stream>>>(q_w, kv_w, proj_w, fc1_w, fc2_w, wcvt);
    k_ln_qkv_mfma<<<6272, 256, 0, stream>>>(x, v, n1g, n1b, nvg, nvb,
                                            qwb, q_b, kvwb, kv_b, qbuf, kbuf, vbuf);
    k_attn_mfma<<<4096, 256, 0, stream>>>(qbuf, kbuf, vbuf, rpb);
    k_proj_mlp<<<6272, 256, 0, stream>>>(qbuf, pwb, proj_b, x, outb,
                                         n2g, n2b, w1b, fc1_b, w2b, fc2_b);
}